// Round 4
// 2899.053 us; speedup vs baseline: 1.2161x; 1.2161x over previous
//
#include <hip/hip_runtime.h>

// GRU (B=64, T=512, I=H=1024) for MI355X / gfx950.
//   phase 0: fp32 -> bf16 converts (input, W_ih, W_hh)
//   phase 1: gi = X @ W_ih^T, bf16 MFMA GEMM (m97-style global_load_lds staging)
//   phase 2: persistent recurrent kernel with TAGGED-WORD h exchange:
//            each h element is one u32 = (step_tag<<16) | bf16(h). A single
//            (naturally atomic) load proves both arrival and value -> no flags,
//            no release fences, no vmcnt(0) drains on the critical path.
//            Groups: 8 groups x 32 blocks (by blockIdx, placement-independent);
//            group x owns batches [8x,8x+8); block slot owns 32 hidden cols.
//            All cross-block traffic uses __hip_atomic_load/store RELAXED AGENT
//            (the exact primitive the verified round-0 kernel used).
//            SAFETY: every spin is bounded (~1M iters); on overflow the block
//            sets `dead` and free-runs to completion -> a protocol stall gives
//            a fast wrong-answer verdict instead of wedging the GPU.
// Protocol safety of slot reuse: slot t&1 holding tag t is only overwritten with
// tag t+2 by a block that already verified ALL of its group's tag-t+1 words;
// each t+1 word is published only after its producer finished reading tag t.
// Hence no reader of tag t can observe t+2 mid-read; stale reads retry on tag.
// Workspace layout:
//   gi   bf16 [32768][3072]          @ 0          (201326592 B)
//   xbf  bf16 [32768][1024]          @ 201326592  (dead after gi_gemm)
//   hbuf u32  [2][64][1024]          @ 201326592  (aliases xbf, 524288 B)
//   wihb bf16 [3072][1024]           @ 268435456
//   whhb bf16 [3072][1024]           @ 274726912

typedef __attribute__((ext_vector_type(8))) short bf16x8;
typedef __attribute__((ext_vector_type(4))) float f32x4;
typedef __attribute__((ext_vector_type(4))) unsigned int uint32x4;

__device__ inline unsigned short f2bf(float f) {
  union { float f; unsigned int u; } x; x.f = f;
  unsigned int r = (x.u + 0x7fffu + ((x.u >> 16) & 1u)) >> 16;  // RNE
  return (unsigned short)r;
}
__device__ inline float bf2f(unsigned short h) {
  union { unsigned int u; float f; } x; x.u = ((unsigned int)h) << 16;
  return x.f;
}
__device__ inline float sigm(float x) { return 1.f / (1.f + __expf(-x)); }
__device__ inline float tanh_f(float x) { float e = __expf(2.f * x); return 1.f - 2.f / (e + 1.f); }

__global__ void cvt_f32_bf16(const float* __restrict__ src, unsigned short* __restrict__ dst, int n4) {
  int i = blockIdx.x * 256 + threadIdx.x;
  if (i >= n4) return;
  float4 v = ((const float4*)src)[i];
  unsigned long long r = (unsigned long long)f2bf(v.x)
                       | ((unsigned long long)f2bf(v.y) << 16)
                       | ((unsigned long long)f2bf(v.z) << 32)
                       | ((unsigned long long)f2bf(v.w) << 48);
  ((unsigned long long*)dst)[i] = r;
}

// hbuf[0][i] = h0 with tag 0; hbuf[1][i] = tag 0xFFFF (never matches a real step).
// Runs after gi_gemm (hbuf aliases xbf); visible to gru_rec via inter-kernel release.
__global__ void init_h(const float* __restrict__ h0, unsigned int* __restrict__ hbuf) {
  int i = blockIdx.x * 256 + threadIdx.x;
  hbuf[i] = (unsigned int)f2bf(h0[i]);
  hbuf[65536 + i] = 0xFFFF0000u;
}

// ---------------- phase 1: gi = X(bf16)[32768x1024] @ W_ih(bf16)[3072x1024]^T -> bf16 [32768x3072]
// (verbatim from the verified baseline)
__global__ __launch_bounds__(256, 2) void gi_gemm(const unsigned short* __restrict__ X,
                                                  const unsigned short* __restrict__ W,
                                                  unsigned short* __restrict__ gi) {
  __shared__ __align__(16) unsigned short As[8192];
  __shared__ __align__(16) unsigned short Bs[8192];
  const int lane = threadIdx.x & 63, wid = threadIdx.x >> 6;
  const int nt = blockIdx.x % 24, mt = blockIdx.x / 24;
  const int m0 = mt * 128, n0 = nt * 128;
  const int wm = wid & 1, wn = wid >> 1;
  const int l15 = lane & 15, l4 = lane >> 4;

  int soff[4];
#pragma unroll
  for (int i = 0; i < 4; ++i) {
    int p = wid * 256 + i * 64 + lane;
    int r = p >> 3, c = (p & 7) ^ (r & 7);
    soff[i] = r * 1024 + c * 8;
  }
  const unsigned short* Xb = X + (size_t)m0 * 1024;
  const unsigned short* Wb = W + (size_t)n0 * 1024;

  f32x4 zero4 = {0.f, 0.f, 0.f, 0.f};
  f32x4 acc[4][4];
#pragma unroll
  for (int a = 0; a < 4; ++a)
#pragma unroll
    for (int b = 0; b < 4; ++b) acc[a][b] = zero4;

  for (int kc = 0; kc < 16; ++kc) {
    __syncthreads();
#pragma unroll
    for (int i = 0; i < 4; ++i) {
      __builtin_amdgcn_global_load_lds(
          (const __attribute__((address_space(1))) unsigned int*)(Xb + kc * 64 + soff[i]),
          (__attribute__((address_space(3))) unsigned int*)(As + (wid * 256 + i * 64) * 8),
          16, 0, 0);
      __builtin_amdgcn_global_load_lds(
          (const __attribute__((address_space(1))) unsigned int*)(Wb + kc * 64 + soff[i]),
          (__attribute__((address_space(3))) unsigned int*)(Bs + (wid * 256 + i * 64) * 8),
          16, 0, 0);
    }
    __syncthreads();
#pragma unroll
    for (int s = 0; s < 2; ++s) {
      const int cc = s * 4 + l4;
      bf16x8 af[4], bfv[4];
#pragma unroll
      for (int ta = 0; ta < 4; ++ta) {
        int r = wm * 64 + ta * 16 + l15;
        int phys = (r << 3) | (cc ^ (r & 7));
        af[ta] = *(const bf16x8*)(As + phys * 8);
      }
#pragma unroll
      for (int tb = 0; tb < 4; ++tb) {
        int r = wn * 64 + tb * 16 + l15;
        int phys = (r << 3) | (cc ^ (r & 7));
        bfv[tb] = *(const bf16x8*)(Bs + phys * 8);
      }
#pragma unroll
      for (int ta = 0; ta < 4; ++ta)
#pragma unroll
        for (int tb = 0; tb < 4; ++tb)
          acc[ta][tb] = __builtin_amdgcn_mfma_f32_16x16x32_bf16(af[ta], bfv[tb], acc[ta][tb], 0, 0, 0);
    }
  }
#pragma unroll
  for (int ta = 0; ta < 4; ++ta)
#pragma unroll
    for (int tb = 0; tb < 4; ++tb) {
      int colg = n0 + wn * 64 + tb * 16 + l15;
#pragma unroll
      for (int rr = 0; rr < 4; ++rr) {
        int rowg = m0 + wm * 64 + ta * 16 + l4 * 4 + rr;
        gi[(size_t)rowg * 3072 + colg] = f2bf(acc[ta][tb][rr]);
      }
    }
}

// lgkm-only barrier: orders LDS traffic without draining vmem (out/h stores stay
// in flight; the tag protocol tolerates in-flight h stores via retry).
__device__ __forceinline__ void barrier_lds() {
  asm volatile("s_waitcnt lgkmcnt(0)" ::: "memory");
  __builtin_amdgcn_s_barrier();
  __builtin_amdgcn_sched_barrier(0);
}

// ---------------- phase 2: group x = blockIdx>>5 owns batches [8x,8x+8);
// slot = blockIdx&31 owns cols [32*slot, 32*slot+32). 4 waves split K=1024.
// W_hh fragments (3 gates x 2 col-halves x 8 ksteps) pinned in 192 VGPRs.
__global__ __launch_bounds__(256, 1) void gru_rec(
    const unsigned short* __restrict__ gi,
    const unsigned short* __restrict__ whh,
    unsigned int* hbuf,
    const int* __restrict__ done,
    const float* __restrict__ h0,
    const float* __restrict__ bih,
    const float* __restrict__ bhh,
    float* __restrict__ out,
    float* __restrict__ hlast) {
  const int tid = threadIdx.x, lane = tid & 63, wid = tid >> 6;
  const int l15 = lane & 15, l4 = lane >> 4;
  const int x = blockIdx.x >> 5, slot = blockIdx.x & 31;
  const int jb = slot * 32;

  __shared__ float cpart[4][6][136];  // [wave][frag][row*17+col], rows 0..7 valid

  // W_hh B-fragments: frag f = gate*2 + colhalf; B row = gate*1024 + jb + colhalf*16 + l15
  uint32x4 wf[8][6];
#pragma unroll
  for (int s = 0; s < 8; ++s)
#pragma unroll
    for (int f = 0; f < 6; ++f) {
      const int row = (f >> 1) * 1024 + jb + (f & 1) * 16 + l15;
      const int k = wid * 256 + s * 32 + l4 * 8;
      wf[s][f] = *(const uint32x4*)(whh + (size_t)row * 1024 + k);
    }
#pragma unroll
  for (int s = 0; s < 8; ++s)
#pragma unroll
    for (int f = 0; f < 6; ++f)
      asm volatile("" : "+v"(wf[s][f]));  // opaque def: pin, no remat in-loop

  // epilogue assignment: one (batch,col) per thread
  const int bb = tid >> 5, jj = tid & 31;
  const int colg = jb + jj;
  const int rowg = x * 8 + bb;
  const float br = bih[colg] + bhh[colg];
  const float bz = bih[1024 + colg] + bhh[1024 + colg];
  const float bni = bih[2048 + colg];
  const float bnh = bhh[2048 + colg];
  float hprev = h0[rowg * 1024 + colg];

  const bool aval = (l15 < 8);           // A rows 8..15 are zero padding
  const int ra = x * 8 + (l15 & 7);      // valid address for every lane
  const int awoff = ra * 1024 + wid * 256 + l4 * 8;  // u32-word offset, chunk s=0
  // cheap spin: wave w covers its 8 producers (slots 8w..8w+7) x 8 rows, 1 word each
  const int rep = (x * 8 + ((lane >> 3) & 7)) * 1024 + (8 * wid + (lane & 7)) * 32;

  int dAr = done[ra * 512];
  int dB = done[rowg * 512];
  unsigned short g0, g1, g2;
  {
    const unsigned short* gp = gi + (size_t)rowg * 512 * 3072 + colg;
    g0 = gp[0]; g1 = gp[1024]; g2 = gp[2048];
  }

  bool dead = false;  // set on spin-guard overflow: free-run, never hang the GPU

#pragma unroll 1
  for (int t = 0; t < 512; ++t) {
    const unsigned int* hb = hbuf + (size_t)(t & 1) * 65536;
    const unsigned tgt = (unsigned)t;

    // 1) representative spin: one word/lane until this wave's 8 producers arrived
    if (!dead) {
      const unsigned int* wp = hb + rep;
      int guard = 0;
      while (true) {
        unsigned v = __hip_atomic_load(wp, __ATOMIC_RELAXED, __HIP_MEMORY_SCOPE_AGENT);
        if (__all((int)((v >> 16) == tgt))) break;
        if (++guard > (1 << 20)) { dead = true; break; }
      }
    }

    // 2) bulk load (u64 = 2 tagged words, naturally atomic), tag-verify, pack.
    //    Immediate pack keeps only 32 VGPRs (aw) live across the retry loop.
    uint32x4 aw[8];
    const unsigned keep = (aval && !dAr) ? 0xffffffffu : 0u;
    {
      const unsigned long long* ap = (const unsigned long long*)hb + (awoff >> 1);
      int guard = 0;
      while (true) {
        unsigned bad = 0u;
        if (aval) {
#pragma unroll
          for (int s = 0; s < 8; ++s)
#pragma unroll
            for (int q = 0; q < 4; ++q) {
              const unsigned long long v =
                  __hip_atomic_load(ap + s * 16 + q, __ATOMIC_RELAXED, __HIP_MEMORY_SCOPE_AGENT);
              bad |= (((unsigned)(v >> 16)) & 0xFFFFu) ^ tgt;
              bad |= ((unsigned)(v >> 48)) ^ tgt;
              aw[s][q] = (((unsigned)(v & 0xFFFFu)) | (((unsigned)(v >> 16)) & 0xFFFF0000u)) & keep;
            }
        } else {
#pragma unroll
          for (int s = 0; s < 8; ++s) aw[s] = uint32x4{0u, 0u, 0u, 0u};
        }
        if (__all((int)(bad == 0u)) || dead) break;
        if (++guard > (1 << 20)) { dead = true; break; }
      }
    }

    // prefetch t+1 inputs now: HBM latency hides under MFMA + epilogue
    int dAr_n = dAr, dB_n = dB;
    unsigned short g0n = g0, g1n = g1, g2n = g2;
    if (t < 511) {
      dAr_n = done[ra * 512 + t + 1];
      dB_n = done[rowg * 512 + t + 1];
      const unsigned short* gp = gi + ((size_t)rowg * 512 + t + 1) * 3072 + colg;
      g0n = gp[0]; g1n = gp[1024]; g2n = gp[2048];
    }

    // 3) MFMA: gh[gate][col] partial sums over this wave's K-quarter
    f32x4 acc0 = {0.f, 0.f, 0.f, 0.f}, acc1 = acc0, acc2 = acc0,
          acc3 = acc0, acc4 = acc0, acc5 = acc0;
#pragma unroll
    for (int s = 0; s < 8; ++s) {
      const bf16x8 af = __builtin_bit_cast(bf16x8, aw[s]);
      acc0 = __builtin_amdgcn_mfma_f32_16x16x32_bf16(af, __builtin_bit_cast(bf16x8, wf[s][0]), acc0, 0, 0, 0);
      acc1 = __builtin_amdgcn_mfma_f32_16x16x32_bf16(af, __builtin_bit_cast(bf16x8, wf[s][1]), acc1, 0, 0, 0);
      acc2 = __builtin_amdgcn_mfma_f32_16x16x32_bf16(af, __builtin_bit_cast(bf16x8, wf[s][2]), acc2, 0, 0, 0);
      acc3 = __builtin_amdgcn_mfma_f32_16x16x32_bf16(af, __builtin_bit_cast(bf16x8, wf[s][3]), acc3, 0, 0, 0);
      acc4 = __builtin_amdgcn_mfma_f32_16x16x32_bf16(af, __builtin_bit_cast(bf16x8, wf[s][4]), acc4, 0, 0, 0);
      acc5 = __builtin_amdgcn_mfma_f32_16x16x32_bf16(af, __builtin_bit_cast(bf16x8, wf[s][5]), acc5, 0, 0, 0);
    }

    if (l4 < 2) {  // C/D: col=lane&15, row=(lane>>4)*4+reg -> rows 0..7 only
#pragma unroll
      for (int rr = 0; rr < 4; ++rr) {
        const int idx = (l4 * 4 + rr) * 17 + l15;
        cpart[wid][0][idx] = acc0[rr];
        cpart[wid][1][idx] = acc1[rr];
        cpart[wid][2][idx] = acc2[rr];
        cpart[wid][3][idx] = acc3[rr];
        cpart[wid][4][idx] = acc4[rr];
        cpart[wid][5][idx] = acc5[rr];
      }
    }
    barrier_lds();

    const int fr = jj >> 4, cc = jj & 15;
    const int ridx = bb * 17 + cc;
    const float ghr = cpart[0][fr][ridx] + cpart[1][fr][ridx] + cpart[2][fr][ridx] + cpart[3][fr][ridx];
    const float ghz = cpart[0][2 + fr][ridx] + cpart[1][2 + fr][ridx] + cpart[2][2 + fr][ridx] + cpart[3][2 + fr][ridx];
    const float ghn = cpart[0][4 + fr][ridx] + cpart[1][4 + fr][ridx] + cpart[2][4 + fr][ridx] + cpart[3][4 + fr][ridx];

    const float hp = dB ? 0.f : hprev;
    const float r = sigm(bf2f(g0) + br + ghr);
    const float z = sigm(bf2f(g1) + bz + ghz);
    const float nn = tanh_f(bf2f(g2) + bni + r * (ghn + bnh));
    const float hn = (1.f - z) * nn + z * hp;
    hprev = hn;

    if (t == 511) {
      out[((size_t)rowg * 512 + t) * 1024 + colg] = hn;
      hlast[rowg * 1024 + colg] = hn;
    } else {
      // publish h FIRST (critical path), then the HBM out store
      unsigned int* dst = hbuf + (size_t)((t + 1) & 1) * 65536 + rowg * 1024 + colg;
      __hip_atomic_store(dst, ((unsigned)(t + 1) << 16) | (unsigned)f2bf(hn),
                         __ATOMIC_RELAXED, __HIP_MEMORY_SCOPE_AGENT);
      out[((size_t)rowg * 512 + t) * 1024 + colg] = hn;
      barrier_lds();  // cpart consumed; no vmem drain
    }
    dAr = dAr_n; dB = dB_n; g0 = g0n; g1 = g1n; g2 = g2n;
  }
}

extern "C" void kernel_launch(void* const* d_in, const int* in_sizes, int n_in,
                              void* d_out, int out_size, void* d_ws, size_t ws_size,
                              hipStream_t stream) {
  const float* x = (const float*)d_in[0];
  const float* h0 = (const float*)d_in[1];
  const int* done = (const int*)d_in[2];
  const float* wih = (const float*)d_in[3];
  const float* whh = (const float*)d_in[4];
  const float* bih = (const float*)d_in[5];
  const float* bhh = (const float*)d_in[6];
  float* out = (float*)d_out;

  char* ws = (char*)d_ws;
  unsigned short* gi = (unsigned short*)(ws);
  unsigned short* xbf = (unsigned short*)(ws + 201326592);
  unsigned short* wihb = (unsigned short*)(ws + 268435456);
  unsigned short* whhb = (unsigned short*)(ws + 274726912);
  unsigned int* hbuf = (unsigned int*)(ws + 201326592);  // aliases xbf (dead after gi_gemm)

  cvt_f32_bf16<<<32768, 256, 0, stream>>>(x, xbf, 8388608);
  cvt_f32_bf16<<<3072, 256, 0, stream>>>(wih, wihb, 786432);
  cvt_f32_bf16<<<3072, 256, 0, stream>>>(whh, whhb, 786432);
  gi_gemm<<<6144, 256, 0, stream>>>(xbf, wihb, gi);
  init_h<<<256, 256, 0, stream>>>(h0, hbuf);
  gru_rec<<<256, 256, 0, stream>>>(gi, whhb, hbuf, done, h0, bih, bhh,
                                   out, out + 33554432);
}